// Round 5
// baseline (1572.504 us; speedup 1.0000x reference)
//
#include <hip/hip_runtime.h>

#define ND 128
#define ED 32
#define HD 256
#define ASTR 296   // edge A-tile LDS row stride (bf16 elems): dword-stride 148=4*37 -> best 16B-aligned spread (2-way, free)
#define NSTR 392   // node A-tile LDS row stride (K=384 + pad), 784B = 49*16

typedef short bf16x8 __attribute__((ext_vector_type(8)));
typedef float f32x4 __attribute__((ext_vector_type(4)));

__device__ __forceinline__ float silu_f(float v) {
  return v / (1.0f + __expf(-v));
}

// v_cvt_pk_bf16_f32: dst.lo = bf16(a), dst.hi = bf16(b)  (RNE)
__device__ __forceinline__ unsigned int cvt_pk_bf16(float a, float b) {
  unsigned int r;
  asm("v_cvt_pk_bf16_f32 %0, %1, %2" : "=v"(r) : "v"(a), "v"(b));
  return r;
}
// split pair (f0,f1) -> packed hi-word + packed lo-word (2x bf16 each)
__device__ __forceinline__ void split_pk(float f0, float f1, unsigned int& hw, unsigned int& lw) {
  hw = cvt_pk_bf16(f0, f1);
  float h0 = __uint_as_float(hw << 16);
  float h1 = __uint_as_float(hw & 0xFFFF0000u);
  lw = cvt_pk_bf16(f0 - h0, f1 - h1);
}
__device__ __forceinline__ void split1(float v, unsigned short& hs, unsigned short& ls) {
  unsigned int hw = cvt_pk_bf16(v, v);
  float hf = __uint_as_float(hw << 16);
  unsigned int lw = cvt_pk_bf16(v - hf, v - hf);
  hs = (unsigned short)hw; ls = (unsigned short)lw;
}
__device__ __forceinline__ void store_split4(unsigned short* hp, unsigned short* lp, float4 v) {
  unsigned int hw0, lw0, hw1, lw1;
  split_pk(v.x, v.y, hw0, lw0);
  split_pk(v.z, v.w, hw1, lw1);
  *reinterpret_cast<uint2*>(hp) = make_uint2(hw0, hw1);
  *reinterpret_cast<uint2*>(lp) = make_uint2(lw0, lw1);
}

// ---------------------------------------------------------------------------
// Pre-split fp32 array into hi/lo bf16 arrays (h matrix; reused 16x per node).
// ---------------------------------------------------------------------------
__global__ void presplit_kernel(const float* __restrict__ src, unsigned short* __restrict__ dh,
                                unsigned short* __restrict__ dl, int total4)
{
  int i = blockIdx.x * 256 + threadIdx.x;
  if (i >= total4) return;
  float4 v = reinterpret_cast<const float4*>(src)[i];
  store_split4(dh + (size_t)i * 4, dl + (size_t)i * 4, v);
}

// ---------------------------------------------------------------------------
// Weight fragment prep: W[K x Ncols] fp32 -> hi/lo bf16 arrays in MFMA B-frag
// order [s][tile][lane][8]:  k = s*32 + (lane>>4)*8 + j,  n = tile*16 + (lane&15).
// skiprow>=0: k >= skiprow maps to W row k+1 (edge dist row handled separately).
// ---------------------------------------------------------------------------
__global__ void prep_frag(const float* __restrict__ W, unsigned short* __restrict__ Fh,
                          unsigned short* __restrict__ Fl, int Keff, int Ncols, int S,
                          int skiprow)
{
  int idx = blockIdx.x * 256 + threadIdx.x;
  int NT = Ncols >> 4;
  int total = S * NT * 64;
  if (idx >= total) return;
  int lane = idx & 63;
  int k0 = (idx / (NT * 64)) * 32 + ((lane >> 4) << 3);
  int n = ((idx >> 6) % NT) * 16 + (lane & 15);
  size_t base = (size_t)idx * 8;
  for (int j = 0; j < 8; ++j) {
    int k = k0 + j;
    float v = 0.f;
    if (k < Keff) {
      int wk = (skiprow >= 0 && k >= skiprow) ? (k + 1) : k;
      v = W[(size_t)wk * Ncols + n];
    }
    unsigned short hi, lo; split1(v, hi, lo);
    Fh[base + j] = hi; Fl[base + j] = lo;
  }
}

// ---------------------------------------------------------------------------
// Split-bf16 MFMA GEMM over a 64-row LDS A-tile.  S compile-time: full unroll
// lets the scheduler overlap next-step A/B loads with current MFMAs.
// A-frag: row = mt*16 + (lane&15), k = s*32 + (lane>>4)*8 + j  (ds_read_b128).
// 3 MFMAs per product: hi*hi + hi*lo + lo*hi (err ~2^-17).
// ---------------------------------------------------------------------------
template<int STRIDE, int NT, int NTW, int S>
__device__ __forceinline__ void mfma_gemm(const unsigned short* __restrict__ Ahi_,
                                          const unsigned short* __restrict__ Alo_,
                                          const unsigned short* __restrict__ Bh,
                                          const unsigned short* __restrict__ Bl,
                                          int wave, int lane, f32x4 acc[4][NTW])
{
  const int tx = lane & 15, tz = lane >> 4;
  #pragma unroll
  for (int s = 0; s < S; ++s) {
    bf16x8 bh[NTW], bl[NTW], ah[4], al[4];
    #pragma unroll
    for (int nt = 0; nt < NTW; ++nt) {
      size_t bidx = ((size_t)(s * NT + wave * NTW + nt) * 64 + lane) * 8;
      bh[nt] = *reinterpret_cast<const bf16x8*>(Bh + bidx);
      bl[nt] = *reinterpret_cast<const bf16x8*>(Bl + bidx);
    }
    const int koff = s * 32 + tz * 8;
    #pragma unroll
    for (int mt = 0; mt < 4; ++mt) {
      size_t aoff = (size_t)(mt * 16 + tx) * STRIDE + koff;
      ah[mt] = *reinterpret_cast<const bf16x8*>(Ahi_ + aoff);
      al[mt] = *reinterpret_cast<const bf16x8*>(Alo_ + aoff);
    }
    __builtin_amdgcn_s_setprio(1);
    #pragma unroll
    for (int mt = 0; mt < 4; ++mt) {
      #pragma unroll
      for (int nt = 0; nt < NTW; ++nt) {
        acc[mt][nt] = __builtin_amdgcn_mfma_f32_16x16x32_bf16(ah[mt], bh[nt], acc[mt][nt], 0, 0, 0);
        acc[mt][nt] = __builtin_amdgcn_mfma_f32_16x16x32_bf16(ah[mt], bl[nt], acc[mt][nt], 0, 0, 0);
        acc[mt][nt] = __builtin_amdgcn_mfma_f32_16x16x32_bf16(al[mt], bh[nt], acc[mt][nt], 0, 0, 0);
      }
    }
    __builtin_amdgcn_s_setprio(0);
  }
}

// ---------------------------------------------------------------------------
// Edge kernel: 64 edges/block, 512 threads (8 waves).
// edge_in LDS cols: [0..127]=h[row], [128..255]=h[col], [256..287]=edge_attr
// (pre-split h copied as bf16; attr split in-kernel via cvt_pk).
// dist_sq handled as exact fp32 rank-1 update with mW1 row 256.
// m_i atomics issued AFTER the overlay barrier so the barrier never drains them.
// LDS: 2*64*296*2B + misc = 77.3 KB -> 2 blocks/CU.
// ---------------------------------------------------------------------------
__global__ __launch_bounds__(512, 4)
void egnn_edge_mfma(const unsigned short* __restrict__ Hh, const unsigned short* __restrict__ Hl,
                    const float* __restrict__ x,
                    const int* __restrict__ eidx, const float* __restrict__ eattr,
                    const float* __restrict__ mW1, const float* __restrict__ mb1,
                    const float* __restrict__ mb2, const float* __restrict__ cb1,
                    const float* __restrict__ cW2,
                    const unsigned short* __restrict__ W1h, const unsigned short* __restrict__ W1l,
                    const unsigned short* __restrict__ W2h, const unsigned short* __restrict__ W2l,
                    const unsigned short* __restrict__ C1h, const unsigned short* __restrict__ C1l,
                    float* __restrict__ m_i, float* __restrict__ x_agg, int E)
{
  __shared__ unsigned short Ahi[64][ASTR];
  __shared__ unsigned short Alo[64][ASTR];
  __shared__ int   sRow[64];
  __shared__ float sDx0[64], sDx1[64], sDx2[64], sDist[64], sCoef[64];

  const int t  = threadIdx.x;
  const int e0 = blockIdx.x * 64;
  if (t < 64) sCoef[t] = 0.f;

  { // ---- stage: 8 threads per edge; h copied pre-split, attr split here ----
    const int e = t >> 3, part = t & 7;
    const int ge = e0 + e;
    if (ge < E) {
      const int r = eidx[ge], c = eidx[E + ge];
      const int node = (part < 4) ? r : c;
      const int cb = (part < 4 ? 0 : 128) + (part & 3) * 32;
      const size_t gb = (size_t)node * ND + (part & 3) * 32;
      #pragma unroll
      for (int i = 0; i < 4; ++i) {
        reinterpret_cast<uint4*>(&Ahi[e][cb])[i] = reinterpret_cast<const uint4*>(Hh + gb)[i];
        reinterpret_cast<uint4*>(&Alo[e][cb])[i] = reinterpret_cast<const uint4*>(Hl + gb)[i];
      }
      float4 av = reinterpret_cast<const float4*>(eattr + (size_t)ge * ED)[part];
      store_split4(&Ahi[e][256 + part * 4], &Alo[e][256 + part * 4], av);
      if (part == 0) {
        sRow[e] = r;
        float d0 = x[3*(size_t)r+0] - x[3*(size_t)c+0];
        float d1 = x[3*(size_t)r+1] - x[3*(size_t)c+1];
        float d2 = x[3*(size_t)r+2] - x[3*(size_t)c+2];
        sDx0[e] = d0; sDx1[e] = d1; sDx2[e] = d2;
        sDist[e] = d0*d0 + d1*d1 + d2*d2 + 1e-8f;
      }
    }
  }
  __syncthreads();

  const int lane = t & 63, wave = t >> 6;
  const int tx = lane & 15, tz = lane >> 4;
  const int c0 = wave * 32 + tx;
  const int c1 = c0 + 16;

  f32x4 acc[4][2];

  // ---- GEMM1: m1 = silu(edge_in @ mW1 + mb1); dist term exact fp32 ----
  {
    const float b0v = mb1[c0], b1v = mb1[c1];
    const float wA = mW1[(size_t)256 * HD + c0];
    const float wB = mW1[(size_t)256 * HD + c1];
    #pragma unroll
    for (int mt = 0; mt < 4; ++mt)
      #pragma unroll
      for (int r = 0; r < 4; ++r) {
        const float d = sDist[mt * 16 + tz * 4 + r];
        acc[mt][0][r] = b0v + d * wA;
        acc[mt][1][r] = b1v + d * wB;
      }
  }
  mfma_gemm<ASTR, 16, 2, 9>(&Ahi[0][0], &Alo[0][0], W1h, W1l, wave, lane, acc);
  __syncthreads();                       // all waves done READING edge_in
  #pragma unroll
  for (int mt = 0; mt < 4; ++mt)
    #pragma unroll
    for (int r = 0; r < 4; ++r) {
      const int row = mt * 16 + tz * 4 + r;
      unsigned short hs, ls;
      split1(silu_f(acc[mt][0][r]), hs, ls);
      Ahi[row][c0] = hs; Alo[row][c0] = ls;
      split1(silu_f(acc[mt][1][r]), hs, ls);
      Ahi[row][c1] = hs; Alo[row][c1] = ls;
    }
  __syncthreads();

  // ---- GEMM2: m = silu(m1 @ mW2 + mb2) ----
  {
    const float b0v = mb2[c0], b1v = mb2[c1];
    #pragma unroll
    for (int mt = 0; mt < 4; ++mt)
      #pragma unroll
      for (int r = 0; r < 4; ++r) { acc[mt][0][r] = b0v; acc[mt][1][r] = b1v; }
  }
  mfma_gemm<ASTR, 16, 2, 8>(&Ahi[0][0], &Alo[0][0], W2h, W2l, wave, lane, acc);
  #pragma unroll
  for (int mt = 0; mt < 4; ++mt)
    #pragma unroll
    for (int r = 0; r < 4; ++r) {
      acc[mt][0][r] = silu_f(acc[mt][0][r]);
      acc[mt][1][r] = silu_f(acc[mt][1][r]);
    }
  __syncthreads();                       // all waves done READING m1
  #pragma unroll
  for (int mt = 0; mt < 4; ++mt)
    #pragma unroll
    for (int r = 0; r < 4; ++r) {
      const int row = mt * 16 + tz * 4 + r;
      unsigned short hs, ls;
      split1(acc[mt][0][r], hs, ls);
      Ahi[row][c0] = hs; Alo[row][c0] = ls;
      split1(acc[mt][1][r], hs, ls);
      Ahi[row][c1] = hs; Alo[row][c1] = ls;
    }
  __syncthreads();                       // m visible in LDS

  // ---- m_i scatter AFTER the barrier: GEMM3 hides the atomic drain ----
  #pragma unroll
  for (int mt = 0; mt < 4; ++mt)
    #pragma unroll
    for (int r = 0; r < 4; ++r) {
      const int row = mt * 16 + tz * 4 + r;
      if (e0 + row < E) {
        const size_t rn = (size_t)sRow[row] * HD;
        unsafeAtomicAdd(&m_i[rn + c0], acc[mt][0][r]);
        unsafeAtomicAdd(&m_i[rn + c1], acc[mt][1][r]);
      }
    }

  // ---- GEMM3: coef = silu(m @ cW1 + cb1) @ cW2 ----
  {
    const float b0v = cb1[c0], b1v = cb1[c1];
    #pragma unroll
    for (int mt = 0; mt < 4; ++mt)
      #pragma unroll
      for (int r = 0; r < 4; ++r) { acc[mt][0][r] = b0v; acc[mt][1][r] = b1v; }
  }
  mfma_gemm<ASTR, 16, 2, 8>(&Ahi[0][0], &Alo[0][0], C1h, C1l, wave, lane, acc);
  {
    const float w20 = cW2[c0], w21 = cW2[c1];
    #pragma unroll
    for (int mt = 0; mt < 4; ++mt)
      #pragma unroll
      for (int r = 0; r < 4; ++r) {
        float v = silu_f(acc[mt][0][r]) * w20 + silu_f(acc[mt][1][r]) * w21;
        v += __shfl_xor(v, 1); v += __shfl_xor(v, 2);
        v += __shfl_xor(v, 4); v += __shfl_xor(v, 8);
        if (tx == 0) atomicAdd(&sCoef[mt * 16 + tz * 4 + r], v);
      }
  }
  __syncthreads();
  if (t < 64 && e0 + t < E) {
    const float cf = sCoef[t];
    const size_t rn = 3 * (size_t)sRow[t];
    unsafeAtomicAdd(&x_agg[rn + 0], sDx0[t] * cf);
    unsafeAtomicAdd(&x_agg[rn + 1], sDx1[t] * cf);
    unsafeAtomicAdd(&x_agg[rn + 2], sDx2[t] * cf);
  }
}

// ---------------------------------------------------------------------------
// Fused node kernel: t1 = silu([h,m_i]@nW1+nb1) (K=384) kept in LDS ->
// h_res = h + t1@nW2 + nb2 (N=128) -> LayerNorm -> h_out.  64 nodes/block.
// ---------------------------------------------------------------------------
__global__ __launch_bounds__(512, 2)
void egnn_node_mfma(const float* __restrict__ h,
                    const unsigned short* __restrict__ Hh, const unsigned short* __restrict__ Hl,
                    const float* __restrict__ m_i,
                    const unsigned short* __restrict__ N1h, const unsigned short* __restrict__ N1l,
                    const unsigned short* __restrict__ N2h, const unsigned short* __restrict__ N2l,
                    const float* __restrict__ nb1, const float* __restrict__ nb2,
                    const float* __restrict__ gamma, const float* __restrict__ beta,
                    float* __restrict__ hout, int N)
{
  __shared__ unsigned short Ahi[64][NSTR];
  __shared__ unsigned short Alo[64][NSTR];
  __shared__ float sSum[64], sSum2[64];

  const int t  = threadIdx.x;
  const int n0 = blockIdx.x * 64;
  if (t < 64) { sSum[t] = 0.f; sSum2[t] = 0.f; }

  { // ---- stage [h | m_i]: h copied pre-split, m_i split via cvt_pk ----
    const int e = t >> 3, part = t & 7;
    const int n = n0 + e;
    if (n < N) {
      const size_t gb = (size_t)n * ND + part * 16;
      #pragma unroll
      for (int i = 0; i < 2; ++i) {
        reinterpret_cast<uint4*>(&Ahi[e][part * 16])[i] = reinterpret_cast<const uint4*>(Hh + gb)[i];
        reinterpret_cast<uint4*>(&Alo[e][part * 16])[i] = reinterpret_cast<const uint4*>(Hl + gb)[i];
      }
      #pragma unroll
      for (int i = 0; i < 8; ++i) {
        float4 v = reinterpret_cast<const float4*>(m_i + (size_t)n * HD + part * 32)[i];
        store_split4(&Ahi[e][128 + part * 32 + i * 4], &Alo[e][128 + part * 32 + i * 4], v);
      }
    }
  }
  __syncthreads();

  const int lane = t & 63, wave = t >> 6;
  const int tx = lane & 15, tz = lane >> 4;

  { // ---- GEMM1: t1 = silu([h,m_i] @ nW1 + nb1), overlay into LDS ----
    const int c0 = wave * 32 + tx, c1 = c0 + 16;
    f32x4 acc[4][2];
    const float b0v = nb1[c0], b1v = nb1[c1];
    #pragma unroll
    for (int mt = 0; mt < 4; ++mt)
      #pragma unroll
      for (int r = 0; r < 4; ++r) { acc[mt][0][r] = b0v; acc[mt][1][r] = b1v; }
    mfma_gemm<NSTR, 16, 2, 12>(&Ahi[0][0], &Alo[0][0], N1h, N1l, wave, lane, acc);
    __syncthreads();
    #pragma unroll
    for (int mt = 0; mt < 4; ++mt)
      #pragma unroll
      for (int r = 0; r < 4; ++r) {
        const int row = mt * 16 + tz * 4 + r;
        unsigned short hs, ls;
        split1(silu_f(acc[mt][0][r]), hs, ls);
        Ahi[row][c0] = hs; Alo[row][c0] = ls;
        split1(silu_f(acc[mt][1][r]), hs, ls);
        Ahi[row][c1] = hs; Alo[row][c1] = ls;
      }
    __syncthreads();
  }

  // ---- GEMM2: h_res = h + t1 @ nW2 + nb2  (N=128: 1 tile/wave) ----
  const int col = wave * 16 + tx;
  f32x4 a2[4][1];
  {
    const float bv = nb2[col];
    #pragma unroll
    for (int mt = 0; mt < 4; ++mt)
      #pragma unroll
      for (int r = 0; r < 4; ++r) a2[mt][0][r] = bv;
  }
  mfma_gemm<NSTR, 8, 1, 8>(&Ahi[0][0], &Alo[0][0], N2h, N2l, wave, lane, a2);

  // ---- epilogue: residual + LayerNorm ----
  const float g  = gamma[col];
  const float bt = beta[col];
  float vv[4][4];
  #pragma unroll
  for (int mt = 0; mt < 4; ++mt)
    #pragma unroll
    for (int r = 0; r < 4; ++r) {
      const int row = mt * 16 + tz * 4 + r;
      const int n = n0 + row;
      const float hv = (n < N) ? h[(size_t)n * ND + col] : 0.f;
      const float v = a2[mt][0][r] + hv;
      vv[mt][r] = v;
      float s1 = v, s2 = v * v;
      s1 += __shfl_xor(s1, 1); s1 += __shfl_xor(s1, 2);
      s1 += __shfl_xor(s1, 4); s1 += __shfl_xor(s1, 8);
      s2 += __shfl_xor(s2, 1); s2 += __shfl_xor(s2, 2);
      s2 += __shfl_xor(s2, 4); s2 += __shfl_xor(s2, 8);
      if (tx == 0) {
        atomicAdd(&sSum[row],  s1);
        atomicAdd(&sSum2[row], s2);
      }
    }
  __syncthreads();
  #pragma unroll
  for (int mt = 0; mt < 4; ++mt)
    #pragma unroll
    for (int r = 0; r < 4; ++r) {
      const int row = mt * 16 + tz * 4 + r;
      const int n = n0 + row;
      if (n < N) {
        const float mu   = sSum[row] * (1.f / 128.f);
        const float var  = sSum2[row] * (1.f / 128.f) - mu * mu;
        const float rstd = rsqrtf(var + 1e-5f);
        hout[(size_t)n * ND + col] = (vv[mt][r] - mu) * rstd * g + bt;
      }
    }
}

__global__ void egnn_xout_kernel(const float* __restrict__ x, const float* __restrict__ x_agg,
                                 float* __restrict__ xout, int total)
{
  int i = blockIdx.x * 256 + threadIdx.x;
  if (i < total) xout[i] = x[i] + x_agg[i];
}

extern "C" void kernel_launch(void* const* d_in, const int* in_sizes, int n_in,
                              void* d_out, int out_size, void* d_ws, size_t ws_size,
                              hipStream_t stream)
{
  const float* h     = (const float*)d_in[0];
  const float* x     = (const float*)d_in[1];
  const int*   eidx  = (const int*)  d_in[2];
  const float* eattr = (const float*)d_in[3];
  const float* mW1   = (const float*)d_in[4];
  const float* mb1   = (const float*)d_in[5];
  const float* mW2   = (const float*)d_in[6];
  const float* mb2   = (const float*)d_in[7];
  const float* nW1   = (const float*)d_in[8];
  const float* nb1   = (const float*)d_in[9];
  const float* nW2   = (const float*)d_in[10];
  const float* nb2   = (const float*)d_in[11];
  const float* cW1   = (const float*)d_in[12];
  const float* cb1   = (const float*)d_in[13];
  const float* cW2   = (const float*)d_in[14];
  const float* gamma = (const float*)d_in[15];
  const float* beta  = (const float*)d_in[16];

  const int N = in_sizes[0] / ND;
  const int E = in_sizes[2] / 2;

  float* m_i   = (float*)d_ws;                       // [N, HD] fp32
  float* x_agg = m_i + (size_t)N * HD;               // [N, 3]  fp32
  unsigned short* fr = (unsigned short*)(x_agg + (size_t)N * 3);

  unsigned short* Hh = fr; fr += (size_t)N * ND;     // pre-split h
  unsigned short* Hl = fr; fr += (size_t)N * ND;

  const int SZ_W1 = 9  * 16 * 64 * 8;   // mW1 frags (K=288 w/ dist-row skip)
  const int SZ_W2 = 8  * 16 * 64 * 8;   // mW2 / cW1 frags (K=256, N=256)
  const int SZ_N1 = 12 * 16 * 64 * 8;   // nW1 frags (K=384, N=256)
  const int SZ_N2 = 8  * 8  * 64 * 8;   // nW2 frags (K=256, N=128)
  unsigned short* W1h = fr; fr += SZ_W1;
  unsigned short* W1l = fr; fr += SZ_W1;
  unsigned short* W2h = fr; fr += SZ_W2;
  unsigned short* W2l = fr; fr += SZ_W2;
  unsigned short* C1h = fr; fr += SZ_W2;
  unsigned short* C1l = fr; fr += SZ_W2;
  unsigned short* N1h = fr; fr += SZ_N1;
  unsigned short* N1l = fr; fr += SZ_N1;
  unsigned short* N2h = fr; fr += SZ_N2;
  unsigned short* N2l = fr; fr += SZ_N2;

  float* hout = (float*)d_out;                       // [N, ND]
  float* xout = hout + (size_t)N * ND;               // [N, 3]

  hipMemsetAsync(m_i,   0, (size_t)N * HD * sizeof(float), stream);
  hipMemsetAsync(x_agg, 0, (size_t)N * 3  * sizeof(float), stream);

  presplit_kernel<<<(N * ND / 4 + 255)/256, 256, 0, stream>>>(h, Hh, Hl, N * ND / 4);
  prep_frag<<<(9*16*64  + 255)/256, 256, 0, stream>>>(mW1, W1h, W1l, 288, 256,  9, 256);
  prep_frag<<<(8*16*64  + 255)/256, 256, 0, stream>>>(mW2, W2h, W2l, 256, 256,  8,  -1);
  prep_frag<<<(8*16*64  + 255)/256, 256, 0, stream>>>(cW1, C1h, C1l, 256, 256,  8,  -1);
  prep_frag<<<(12*16*64 + 255)/256, 256, 0, stream>>>(nW1, N1h, N1l, 384, 256, 12,  -1);
  prep_frag<<<(8*8*64   + 255)/256, 256, 0, stream>>>(nW2, N2h, N2l, 256, 128,  8,  -1);

  egnn_edge_mfma<<<(E + 63) / 64, 512, 0, stream>>>(
      Hh, Hl, x, eidx, eattr, mW1, mb1, mb2, cb1, cW2,
      W1h, W1l, W2h, W2l, C1h, C1l, m_i, x_agg, E);
  egnn_node_mfma<<<(N + 63) / 64, 512, 0, stream>>>(
      h, Hh, Hl, m_i, N1h, N1l, N2h, N2l, nb1, nb2, gamma, beta, hout, N);
  egnn_xout_kernel<<<(N * 3 + 255) / 256, 256, 0, stream>>>(x, x_agg, xout, N * 3);
}

// Round 6
// 1388.965 us; speedup vs baseline: 1.1321x; 1.1321x over previous
//
#include <hip/hip_runtime.h>

#define ND 128
#define ED 32
#define HD 256
#define ASTR 296   // edge A-tile LDS row stride (bf16): dword-stride 148=4*37, 2-way bank alias (free)
#define NSTR 392   // node A-tile LDS row stride (K=384 + pad)

typedef short bf16x8 __attribute__((ext_vector_type(8)));
typedef float f32x4 __attribute__((ext_vector_type(4)));

__device__ __forceinline__ float silu_f(float v) {
  return v / (1.0f + __expf(-v));
}

// v_cvt_pk_bf16_f32: dst.lo = bf16(a), dst.hi = bf16(b)  (RNE)
__device__ __forceinline__ unsigned int cvt_pk_bf16(float a, float b) {
  unsigned int r;
  asm("v_cvt_pk_bf16_f32 %0, %1, %2" : "=v"(r) : "v"(a), "v"(b));
  return r;
}
__device__ __forceinline__ void split_pk(float f0, float f1, unsigned int& hw, unsigned int& lw) {
  hw = cvt_pk_bf16(f0, f1);
  float h0 = __uint_as_float(hw << 16);
  float h1 = __uint_as_float(hw & 0xFFFF0000u);
  lw = cvt_pk_bf16(f0 - h0, f1 - h1);
}
__device__ __forceinline__ void split1(float v, unsigned short& hs, unsigned short& ls) {
  unsigned int hw = cvt_pk_bf16(v, v);
  float hf = __uint_as_float(hw << 16);
  unsigned int lw = cvt_pk_bf16(v - hf, v - hf);
  hs = (unsigned short)hw; ls = (unsigned short)lw;
}
__device__ __forceinline__ void store_split4(unsigned short* hp, unsigned short* lp, float4 v) {
  unsigned int hw0, lw0, hw1, lw1;
  split_pk(v.x, v.y, hw0, lw0);
  split_pk(v.z, v.w, hw1, lw1);
  *reinterpret_cast<uint2*>(hp) = make_uint2(hw0, hw1);
  *reinterpret_cast<uint2*>(lp) = make_uint2(lw0, lw1);
}

// ---------------------------------------------------------------------------
// Pre-split fp32 array into hi/lo bf16 arrays (h is gathered ~16x per node).
// ---------------------------------------------------------------------------
__global__ void presplit_kernel(const float* __restrict__ src, unsigned short* __restrict__ dh,
                                unsigned short* __restrict__ dl, int total4)
{
  int i = blockIdx.x * 256 + threadIdx.x;
  if (i >= total4) return;
  float4 v = reinterpret_cast<const float4*>(src)[i];
  store_split4(dh + (size_t)i * 4, dl + (size_t)i * 4, v);
}

// ---------------------------------------------------------------------------
// Weight fragment prep: W[K x Ncols] fp32 -> hi/lo bf16 in MFMA B-frag order
// [s][tile][lane][8]:  k = s*32 + (lane>>4)*8 + j,  n = tile*16 + (lane&15).
// skiprow>=0: k >= skiprow maps to W row k+1 (edge dist row handled separately).
// ---------------------------------------------------------------------------
__global__ void prep_frag(const float* __restrict__ W, unsigned short* __restrict__ Fh,
                          unsigned short* __restrict__ Fl, int Keff, int Ncols, int S,
                          int skiprow)
{
  int idx = blockIdx.x * 256 + threadIdx.x;
  int NT = Ncols >> 4;
  int total = S * NT * 64;
  if (idx >= total) return;
  int lane = idx & 63;
  int k0 = (idx / (NT * 64)) * 32 + ((lane >> 4) << 3);
  int n = ((idx >> 6) % NT) * 16 + (lane & 15);
  size_t base = (size_t)idx * 8;
  for (int j = 0; j < 8; ++j) {
    int k = k0 + j;
    float v = 0.f;
    if (k < Keff) {
      int wk = (skiprow >= 0 && k >= skiprow) ? (k + 1) : k;
      v = W[(size_t)wk * Ncols + n];
    }
    unsigned short hi, lo; split1(v, hi, lo);
    Fh[base + j] = hi; Fl[base + j] = lo;
  }
}

// ---------------------------------------------------------------------------
// Split-bf16 MFMA GEMM over a 64-row LDS A-tile.  S is RUNTIME (round-5
// full-unroll blew the I-cache: +16KB/block FETCH, MfmaUtil 39->35 — reverted).
// A-frag: row = mt*16 + (lane&15), k = s*32 + (lane>>4)*8 + j  (ds_read_b128).
// 3 MFMAs per product: hi*hi + hi*lo + lo*hi (err ~2^-17).
// ---------------------------------------------------------------------------
template<int STRIDE, int NT, int NTW>
__device__ __forceinline__ void mfma_gemm(const unsigned short* __restrict__ Ahi_,
                                          const unsigned short* __restrict__ Alo_,
                                          const unsigned short* __restrict__ Bh,
                                          const unsigned short* __restrict__ Bl,
                                          int S, int wave, int lane, f32x4 acc[4][NTW])
{
  const int tx = lane & 15, tz = lane >> 4;
  for (int s = 0; s < S; ++s) {
    bf16x8 bh[NTW], bl[NTW], ah[4], al[4];
    #pragma unroll
    for (int nt = 0; nt < NTW; ++nt) {
      size_t bidx = ((size_t)(s * NT + wave * NTW + nt) * 64 + lane) * 8;
      bh[nt] = *reinterpret_cast<const bf16x8*>(Bh + bidx);
      bl[nt] = *reinterpret_cast<const bf16x8*>(Bl + bidx);
    }
    const int koff = s * 32 + tz * 8;
    #pragma unroll
    for (int mt = 0; mt < 4; ++mt) {
      size_t aoff = (size_t)(mt * 16 + tx) * STRIDE + koff;
      ah[mt] = *reinterpret_cast<const bf16x8*>(Ahi_ + aoff);
      al[mt] = *reinterpret_cast<const bf16x8*>(Alo_ + aoff);
    }
    #pragma unroll
    for (int mt = 0; mt < 4; ++mt) {
      #pragma unroll
      for (int nt = 0; nt < NTW; ++nt) {
        acc[mt][nt] = __builtin_amdgcn_mfma_f32_16x16x32_bf16(ah[mt], bh[nt], acc[mt][nt], 0, 0, 0);
        acc[mt][nt] = __builtin_amdgcn_mfma_f32_16x16x32_bf16(ah[mt], bl[nt], acc[mt][nt], 0, 0, 0);
        acc[mt][nt] = __builtin_amdgcn_mfma_f32_16x16x32_bf16(al[mt], bh[nt], acc[mt][nt], 0, 0, 0);
      }
    }
  }
}

// ---------------------------------------------------------------------------
// Edge kernel: 64 edges/block, 512 threads (8 waves).  Round-3 phase order;
// staging uses pre-split h (VALUBusy 52->41 proven) + cvt_pk for attr.
// LDS: 2*64*296*2B + misc = 77.3 KB -> 2 blocks/CU.
// ---------------------------------------------------------------------------
__global__ __launch_bounds__(512, 4)
void egnn_edge_mfma(const unsigned short* __restrict__ Hh, const unsigned short* __restrict__ Hl,
                    const float* __restrict__ x,
                    const int* __restrict__ eidx, const float* __restrict__ eattr,
                    const float* __restrict__ mW1, const float* __restrict__ mb1,
                    const float* __restrict__ mb2, const float* __restrict__ cb1,
                    const float* __restrict__ cW2,
                    const unsigned short* __restrict__ W1h, const unsigned short* __restrict__ W1l,
                    const unsigned short* __restrict__ W2h, const unsigned short* __restrict__ W2l,
                    const unsigned short* __restrict__ C1h, const unsigned short* __restrict__ C1l,
                    float* __restrict__ m_i, float* __restrict__ x_agg, int E)
{
  __shared__ unsigned short Ahi[64][ASTR];
  __shared__ unsigned short Alo[64][ASTR];
  __shared__ int   sRow[64];
  __shared__ float sDx0[64], sDx1[64], sDx2[64], sDist[64], sCoef[64];

  const int t  = threadIdx.x;
  const int e0 = blockIdx.x * 64;
  if (t < 64) sCoef[t] = 0.f;

  { // ---- stage: 8 threads per edge; h copied pre-split, attr split here ----
    const int e = t >> 3, part = t & 7;
    const int ge = e0 + e;
    if (ge < E) {
      const int r = eidx[ge], c = eidx[E + ge];
      const int node = (part < 4) ? r : c;
      const int cb = (part < 4 ? 0 : 128) + (part & 3) * 32;
      const size_t gb = (size_t)node * ND + (part & 3) * 32;
      #pragma unroll
      for (int i = 0; i < 4; ++i) {
        reinterpret_cast<uint4*>(&Ahi[e][cb])[i] = reinterpret_cast<const uint4*>(Hh + gb)[i];
        reinterpret_cast<uint4*>(&Alo[e][cb])[i] = reinterpret_cast<const uint4*>(Hl + gb)[i];
      }
      float4 av = reinterpret_cast<const float4*>(eattr + (size_t)ge * ED)[part];
      store_split4(&Ahi[e][256 + part * 4], &Alo[e][256 + part * 4], av);
      if (part == 0) {
        sRow[e] = r;
        float d0 = x[3*(size_t)r+0] - x[3*(size_t)c+0];
        float d1 = x[3*(size_t)r+1] - x[3*(size_t)c+1];
        float d2 = x[3*(size_t)r+2] - x[3*(size_t)c+2];
        sDx0[e] = d0; sDx1[e] = d1; sDx2[e] = d2;
        sDist[e] = d0*d0 + d1*d1 + d2*d2 + 1e-8f;
      }
    }
  }
  __syncthreads();

  const int lane = t & 63, wave = t >> 6;
  const int tx = lane & 15, tz = lane >> 4;
  const int c0 = wave * 32 + tx;
  const int c1 = c0 + 16;

  f32x4 acc[4][2];

  // ---- GEMM1: m1 = silu(edge_in @ mW1 + mb1); dist term exact fp32 ----
  {
    const float b0v = mb1[c0], b1v = mb1[c1];
    const float wA = mW1[(size_t)256 * HD + c0];
    const float wB = mW1[(size_t)256 * HD + c1];
    #pragma unroll
    for (int mt = 0; mt < 4; ++mt)
      #pragma unroll
      for (int r = 0; r < 4; ++r) {
        const float d = sDist[mt * 16 + tz * 4 + r];
        acc[mt][0][r] = b0v + d * wA;
        acc[mt][1][r] = b1v + d * wB;
      }
  }
  mfma_gemm<ASTR, 16, 2>(&Ahi[0][0], &Alo[0][0], W1h, W1l, 9, wave, lane, acc);
  __syncthreads();                       // all waves done READING edge_in
  #pragma unroll
  for (int mt = 0; mt < 4; ++mt)
    #pragma unroll
    for (int r = 0; r < 4; ++r) {
      const int row = mt * 16 + tz * 4 + r;
      unsigned short hs, ls;
      split1(silu_f(acc[mt][0][r]), hs, ls);
      Ahi[row][c0] = hs; Alo[row][c0] = ls;
      split1(silu_f(acc[mt][1][r]), hs, ls);
      Ahi[row][c1] = hs; Alo[row][c1] = ls;
    }
  __syncthreads();

  // ---- GEMM2: m = silu(m1 @ mW2 + mb2); scatter m_i (round-3 position) ----
  {
    const float b0v = mb2[c0], b1v = mb2[c1];
    #pragma unroll
    for (int mt = 0; mt < 4; ++mt)
      #pragma unroll
      for (int r = 0; r < 4; ++r) { acc[mt][0][r] = b0v; acc[mt][1][r] = b1v; }
  }
  mfma_gemm<ASTR, 16, 2>(&Ahi[0][0], &Alo[0][0], W2h, W2l, 8, wave, lane, acc);
  #pragma unroll
  for (int mt = 0; mt < 4; ++mt)
    #pragma unroll
    for (int r = 0; r < 4; ++r) {
      acc[mt][0][r] = silu_f(acc[mt][0][r]);
      acc[mt][1][r] = silu_f(acc[mt][1][r]);
      const int row = mt * 16 + tz * 4 + r;
      if (e0 + row < E) {
        const size_t rn = (size_t)sRow[row] * HD;
        unsafeAtomicAdd(&m_i[rn + c0], acc[mt][0][r]);
        unsafeAtomicAdd(&m_i[rn + c1], acc[mt][1][r]);
      }
    }
  __syncthreads();                       // all waves done READING m1
  #pragma unroll
  for (int mt = 0; mt < 4; ++mt)
    #pragma unroll
    for (int r = 0; r < 4; ++r) {
      const int row = mt * 16 + tz * 4 + r;
      unsigned short hs, ls;
      split1(acc[mt][0][r], hs, ls);
      Ahi[row][c0] = hs; Alo[row][c0] = ls;
      split1(acc[mt][1][r], hs, ls);
      Ahi[row][c1] = hs; Alo[row][c1] = ls;
    }
  __syncthreads();

  // ---- GEMM3: coef = silu(m @ cW1 + cb1) @ cW2 ----
  {
    const float b0v = cb1[c0], b1v = cb1[c1];
    #pragma unroll
    for (int mt = 0; mt < 4; ++mt)
      #pragma unroll
      for (int r = 0; r < 4; ++r) { acc[mt][0][r] = b0v; acc[mt][1][r] = b1v; }
  }
  mfma_gemm<ASTR, 16, 2>(&Ahi[0][0], &Alo[0][0], C1h, C1l, 8, wave, lane, acc);
  {
    const float w20 = cW2[c0], w21 = cW2[c1];
    #pragma unroll
    for (int mt = 0; mt < 4; ++mt)
      #pragma unroll
      for (int r = 0; r < 4; ++r) {
        float v = silu_f(acc[mt][0][r]) * w20 + silu_f(acc[mt][1][r]) * w21;
        v += __shfl_xor(v, 1); v += __shfl_xor(v, 2);
        v += __shfl_xor(v, 4); v += __shfl_xor(v, 8);
        if (tx == 0) atomicAdd(&sCoef[mt * 16 + tz * 4 + r], v);
      }
  }
  __syncthreads();
  if (t < 64 && e0 + t < E) {
    const float cf = sCoef[t];
    const size_t rn = 3 * (size_t)sRow[t];
    unsafeAtomicAdd(&x_agg[rn + 0], sDx0[t] * cf);
    unsafeAtomicAdd(&x_agg[rn + 1], sDx1[t] * cf);
    unsafeAtomicAdd(&x_agg[rn + 2], sDx2[t] * cf);
  }
}

// ---------------------------------------------------------------------------
// Fused node kernel: t1 = silu([h,m_i]@nW1+nb1) (K=384) kept in LDS ->
// h_res = h + t1@nW2 + nb2 (N=128) -> LayerNorm -> h_out.  64 nodes/block.
// ---------------------------------------------------------------------------
__global__ __launch_bounds__(512, 2)
void egnn_node_mfma(const float* __restrict__ h,
                    const unsigned short* __restrict__ Hh, const unsigned short* __restrict__ Hl,
                    const float* __restrict__ m_i,
                    const unsigned short* __restrict__ N1h, const unsigned short* __restrict__ N1l,
                    const unsigned short* __restrict__ N2h, const unsigned short* __restrict__ N2l,
                    const float* __restrict__ nb1, const float* __restrict__ nb2,
                    const float* __restrict__ gamma, const float* __restrict__ beta,
                    float* __restrict__ hout, int N)
{
  __shared__ unsigned short Ahi[64][NSTR];
  __shared__ unsigned short Alo[64][NSTR];
  __shared__ float sSum[64], sSum2[64];

  const int t  = threadIdx.x;
  const int n0 = blockIdx.x * 64;
  if (t < 64) { sSum[t] = 0.f; sSum2[t] = 0.f; }

  { // ---- stage [h | m_i]: h copied pre-split, m_i split via cvt_pk ----
    const int e = t >> 3, part = t & 7;
    const int n = n0 + e;
    if (n < N) {
      const size_t gb = (size_t)n * ND + part * 16;
      #pragma unroll
      for (int i = 0; i < 2; ++i) {
        reinterpret_cast<uint4*>(&Ahi[e][part * 16])[i] = reinterpret_cast<const uint4*>(Hh + gb)[i];
        reinterpret_cast<uint4*>(&Alo[e][part * 16])[i] = reinterpret_cast<const uint4*>(Hl + gb)[i];
      }
      #pragma unroll
      for (int i = 0; i < 8; ++i) {
        float4 v = reinterpret_cast<const float4*>(m_i + (size_t)n * HD + part * 32)[i];
        store_split4(&Ahi[e][128 + part * 32 + i * 4], &Alo[e][128 + part * 32 + i * 4], v);
      }
    }
  }
  __syncthreads();

  const int lane = t & 63, wave = t >> 6;
  const int tx = lane & 15, tz = lane >> 4;

  { // ---- GEMM1: t1 = silu([h,m_i] @ nW1 + nb1), overlay into LDS ----
    const int c0 = wave * 32 + tx, c1 = c0 + 16;
    f32x4 acc[4][2];
    const float b0v = nb1[c0], b1v = nb1[c1];
    #pragma unroll
    for (int mt = 0; mt < 4; ++mt)
      #pragma unroll
      for (int r = 0; r < 4; ++r) { acc[mt][0][r] = b0v; acc[mt][1][r] = b1v; }
    mfma_gemm<NSTR, 16, 2>(&Ahi[0][0], &Alo[0][0], N1h, N1l, 12, wave, lane, acc);
    __syncthreads();
    #pragma unroll
    for (int mt = 0; mt < 4; ++mt)
      #pragma unroll
      for (int r = 0; r < 4; ++r) {
        const int row = mt * 16 + tz * 4 + r;
        unsigned short hs, ls;
        split1(silu_f(acc[mt][0][r]), hs, ls);
        Ahi[row][c0] = hs; Alo[row][c0] = ls;
        split1(silu_f(acc[mt][1][r]), hs, ls);
        Ahi[row][c1] = hs; Alo[row][c1] = ls;
      }
    __syncthreads();
  }

  // ---- GEMM2: h_res = h + t1 @ nW2 + nb2  (N=128: 1 tile/wave) ----
  const int col = wave * 16 + tx;
  f32x4 a2[4][1];
  {
    const float bv = nb2[col];
    #pragma unroll
    for (int mt = 0; mt < 4; ++mt)
      #pragma unroll
      for (int r = 0; r < 4; ++r) a2[mt][0][r] = bv;
  }
  mfma_gemm<NSTR, 8, 1>(&Ahi[0][0], &Alo[0][0], N2h, N2l, 8, wave, lane, a2);

  // ---- epilogue: residual + LayerNorm ----
  const float g  = gamma[col];
  const float bt = beta[col];
  float vv[4][4];
  #pragma unroll
  for (int mt = 0; mt < 4; ++mt)
    #pragma unroll
    for (int r = 0; r < 4; ++r) {
      const int row = mt * 16 + tz * 4 + r;
      const int n = n0 + row;
      const float hv = (n < N) ? h[(size_t)n * ND + col] : 0.f;
      const float v = a2[mt][0][r] + hv;
      vv[mt][r] = v;
      float s1 = v, s2 = v * v;
      s1 += __shfl_xor(s1, 1); s1 += __shfl_xor(s1, 2);
      s1 += __shfl_xor(s1, 4); s1 += __shfl_xor(s1, 8);
      s2 += __shfl_xor(s2, 1); s2 += __shfl_xor(s2, 2);
      s2 += __shfl_xor(s2, 4); s2 += __shfl_xor(s2, 8);
      if (tx == 0) {
        atomicAdd(&sSum[row],  s1);
        atomicAdd(&sSum2[row], s2);
      }
    }
  __syncthreads();
  #pragma unroll
  for (int mt = 0; mt < 4; ++mt)
    #pragma unroll
    for (int r = 0; r < 4; ++r) {
      const int row = mt * 16 + tz * 4 + r;
      const int n = n0 + row;
      if (n < N) {
        const float mu   = sSum[row] * (1.f / 128.f);
        const float var  = sSum2[row] * (1.f / 128.f) - mu * mu;
        const float rstd = rsqrtf(var + 1e-5f);
        hout[(size_t)n * ND + col] = (vv[mt][r] - mu) * rstd * g + bt;
      }
    }
}

__global__ void egnn_xout_kernel(const float* __restrict__ x, const float* __restrict__ x_agg,
                                 float* __restrict__ xout, int total)
{
  int i = blockIdx.x * 256 + threadIdx.x;
  if (i < total) xout[i] = x[i] + x_agg[i];
}

extern "C" void kernel_launch(void* const* d_in, const int* in_sizes, int n_in,
                              void* d_out, int out_size, void* d_ws, size_t ws_size,
                              hipStream_t stream)
{
  const float* h     = (const float*)d_in[0];
  const float* x     = (const float*)d_in[1];
  const int*   eidx  = (const int*)  d_in[2];
  const float* eattr = (const float*)d_in[3];
  const float* mW1   = (const float*)d_in[4];
  const float* mb1   = (const float*)d_in[5];
  const float* mW2   = (const float*)d_in[6];
  const float* mb2   = (const float*)d_in[7];
  const float* nW1   = (const float*)d_in[8];
  const float* nb1   = (const float*)d_in[9];
  const float* nW2   = (const float*)d_in[10];
  const float* nb2   = (const float*)d_in[11];
  const float* cW1   = (const float*)d_in[12];
  const float* cb1   = (const float*)d_in[13];
  const float* cW2   = (const float*)d_in[14];
  const float* gamma = (const float*)d_in[15];
  const float* beta  = (const float*)d_in[16];

  const int N = in_sizes[0] / ND;
  const int E = in_sizes[2] / 2;

  float* m_i   = (float*)d_ws;                       // [N, HD] fp32
  float* x_agg = m_i + (size_t)N * HD;               // [N, 3]  fp32
  unsigned short* fr = (unsigned short*)(x_agg + (size_t)N * 3);

  unsigned short* Hh = fr; fr += (size_t)N * ND;     // pre-split h
  unsigned short* Hl = fr; fr += (size_t)N * ND;

  const int SZ_W1 = 9  * 16 * 64 * 8;   // mW1 frags (K=288 w/ dist-row skip)
  const int SZ_W2 = 8  * 16 * 64 * 8;   // mW2 / cW1 frags (K=256, N=256)
  const int SZ_N1 = 12 * 16 * 64 * 8;   // nW1 frags (K=384, N=256)
  const int SZ_N2 = 8  * 8  * 64 * 8;   // nW2 frags (K=256, N=128)
  unsigned short* W1h = fr; fr += SZ_W1;
  unsigned short* W1l = fr; fr += SZ_W1;
  unsigned short* W2h = fr; fr += SZ_W2;
  unsigned short* W2l = fr; fr += SZ_W2;
  unsigned short* C1h = fr; fr += SZ_W2;
  unsigned short* C1l = fr; fr += SZ_W2;
  unsigned short* N1h = fr; fr += SZ_N1;
  unsigned short* N1l = fr; fr += SZ_N1;
  unsigned short* N2h = fr; fr += SZ_N2;
  unsigned short* N2l = fr; fr += SZ_N2;

  float* hout = (float*)d_out;                       // [N, ND]
  float* xout = hout + (size_t)N * ND;               // [N, 3]

  hipMemsetAsync(m_i,   0, (size_t)N * HD * sizeof(float), stream);
  hipMemsetAsync(x_agg, 0, (size_t)N * 3  * sizeof(float), stream);

  presplit_kernel<<<(N * ND / 4 + 255)/256, 256, 0, stream>>>(h, Hh, Hl, N * ND / 4);
  prep_frag<<<(9*16*64  + 255)/256, 256, 0, stream>>>(mW1, W1h, W1l, 288, 256,  9, 256);
  prep_frag<<<(8*16*64  + 255)/256, 256, 0, stream>>>(mW2, W2h, W2l, 256, 256,  8,  -1);
  prep_frag<<<(8*16*64  + 255)/256, 256, 0, stream>>>(cW1, C1h, C1l, 256, 256,  8,  -1);
  prep_frag<<<(12*16*64 + 255)/256, 256, 0, stream>>>(nW1, N1h, N1l, 384, 256, 12,  -1);
  prep_frag<<<(8*8*64   + 255)/256, 256, 0, stream>>>(nW2, N2h, N2l, 256, 128,  8,  -1);

  egnn_edge_mfma<<<(E + 63) / 64, 512, 0, stream>>>(
      Hh, Hl, x, eidx, eattr, mW1, mb1, mb2, cb1, cW2,
      W1h, W1l, W2h, W2l, C1h, C1l, m_i, x_agg, E);
  egnn_node_mfma<<<(N + 63) / 64, 512, 0, stream>>>(
      h, Hh, Hl, m_i, N1h, N1l, N2h, N2l, nb1, nb2, gamma, beta, hout, N);
  egnn_xout_kernel<<<(N * 3 + 255) / 256, 256, 0, stream>>>(x, x_agg, xout, N * 3);
}